// Round 14
// baseline (346.070 us; speedup 1.0000x reference)
//
#include <hip/hip_runtime.h>
#include <hip/hip_bf16.h>

#define C 128
#define RBFD 20
#define NATOMS 50000
#define SCAN_CHUNK 1024
#define SLAB 128          // edges per gather block; 800000 % 128 == 0
#define SS 32             // sub-slab size (edges per pipeline stage)

// ---------------------------------------------------------------------------
// Kernel 1: setup — transpose W1, W2 into [in][out], zero histogram counters,
// zero the accumulator.
// ---------------------------------------------------------------------------
__global__ __launch_bounds__(256) void setup_kernel(
    const float* __restrict__ W1, const float* __restrict__ W2,
    float* __restrict__ W1T, float* __restrict__ W2T,
    int* __restrict__ count, float4* __restrict__ acc4,
    int n, int acc_quads)
{
    const int t = blockIdx.x * blockDim.x + threadIdx.x;
    const int stride = gridDim.x * blockDim.x;
    if (t < C * C) {
        int k = t / C;
        int c = t % C;
        W1T[t] = W1[c * C + k];
        W2T[t] = W2[c * C + k];
    }
    for (int i = t; i < n; i += stride) count[i] = 0;
    const float4 z = make_float4(0.f, 0.f, 0.f, 0.f);
    for (int i = t; i < acc_quads; i += stride) acc4[i] = z;
}

// ---------------------------------------------------------------------------
// CSR construction: histogram -> hierarchical exclusive scan -> perm fill
// ---------------------------------------------------------------------------
__global__ __launch_bounds__(256) void histogram_kernel(
    const int* __restrict__ idx, int* __restrict__ count, int E)
{
    int e = blockIdx.x * blockDim.x + threadIdx.x;
    if (e < E) atomicAdd(&count[idx[e]], 1);
}

__global__ __launch_bounds__(256) void scan_partials_kernel(
    const int* __restrict__ count, int* __restrict__ partial, int n)
{
    __shared__ int sm[256];
    const int start = blockIdx.x * SCAN_CHUNK;
    int s = 0;
    for (int i = threadIdx.x; i < SCAN_CHUNK; i += 256) {
        int g = start + i;
        if (g < n) s += count[g];
    }
    sm[threadIdx.x] = s;
    __syncthreads();
    for (int off = 128; off > 0; off >>= 1) {
        if (threadIdx.x < off) sm[threadIdx.x] += sm[threadIdx.x + off];
        __syncthreads();
    }
    if (threadIdx.x == 0) partial[blockIdx.x] = sm[0];
}

__global__ void scan_chunkbase_kernel(int* __restrict__ partial,
                                      int* __restrict__ base,
                                      int nchunks, int n)
{
    if (threadIdx.x == 0 && blockIdx.x == 0) {
        int run = 0;
        for (int k = 0; k < nchunks; ++k) {
            int t = partial[k];
            partial[k] = run;
            run += t;
        }
        base[n] = run;
    }
}

__global__ __launch_bounds__(1024) void scan_apply_kernel(
    const int* __restrict__ count, const int* __restrict__ chunk_base,
    int* __restrict__ base, int* __restrict__ cursor, int n)
{
    __shared__ int sm[SCAN_CHUNK];
    const int t = threadIdx.x;
    const int i = blockIdx.x * SCAN_CHUNK + t;
    int v = (i < n) ? count[i] : 0;
    sm[t] = v;
    __syncthreads();
    for (int off = 1; off < SCAN_CHUNK; off <<= 1) {
        int tmp = (t >= off) ? sm[t - off] : 0;
        __syncthreads();
        sm[t] += tmp;
        __syncthreads();
    }
    if (i < n) {
        int excl = sm[t] - v + chunk_base[blockIdx.x];
        base[i] = excl;
        cursor[i] = excl;
    }
}

__global__ __launch_bounds__(256) void fill_perm_kernel(
    const int* __restrict__ idx, int* __restrict__ cursor,
    int* __restrict__ perm, int* __restrict__ own, int E)
{
    int e = blockIdx.x * blockDim.x + threadIdx.x;
    if (e < E) {
        int a = idx[e];
        int pos = atomicAdd(&cursor[a], 1);
        perm[pos] = e;
        own[pos] = a;
    }
}

// ---------------------------------------------------------------------------
// Gather kernel v11: r10 structure (cooperative rbf->LDS ping-pong, x in
// registers, segmented flush) but with ALL in-loop VMEM loads in inline asm
// and hand-counted s_waitcnt vmcnt(N) — the compiler can neither sink the
// loads to their uses (MachineSink, the r7..r13 failure) nor insert
// conservative drains.  After the initial __syncthreads (vmcnt==0 baseline)
// the only VMEM ops in the loop are our 37 asm loads per stage + rare flush
// stores (which only make waits more conservative).
//
// Steady-state wait math (issue order: rbf(ss+1) x5, then x(ss+1) x32):
//   consume x(ss)[j..j+7]  : newer ops = (24-j) x(ss) + 5 rbf + 32 x  -> vmcnt(61-j)
//   ds_write rbf(ss+1)     : newer ops = 32 x(ss+1)                  -> vmcnt(32)
//   last stage (no issue)  : vmcnt(24/16/8/0)
// Raw s_barrier after lgkmcnt(0): no vmcnt drain crosses the barrier.
// ---------------------------------------------------------------------------
#define WAITV_(n) asm volatile("s_waitcnt vmcnt(" #n ")" ::: "memory")
#define WAITV(n)  WAITV_(n)

__device__ __forceinline__ float filt20(const float* __restrict__ row,
                                        const float* __restrict__ w,
                                        float bias) {
    const float4* q = reinterpret_cast<const float4*>(row);
    const float4 a = q[0], b = q[1], c = q[2], d = q[3], e4 = q[4];
    float f = bias;
    f = fmaf(a.x,  w[0],  f); f = fmaf(a.y,  w[1],  f);
    f = fmaf(a.z,  w[2],  f); f = fmaf(a.w,  w[3],  f);
    f = fmaf(b.x,  w[4],  f); f = fmaf(b.y,  w[5],  f);
    f = fmaf(b.z,  w[6],  f); f = fmaf(b.w,  w[7],  f);
    f = fmaf(c.x,  w[8],  f); f = fmaf(c.y,  w[9],  f);
    f = fmaf(c.z,  w[10], f); f = fmaf(c.w,  w[11], f);
    f = fmaf(d.x,  w[12], f); f = fmaf(d.y,  w[13], f);
    f = fmaf(d.z,  w[14], f); f = fmaf(d.w,  w[15], f);
    f = fmaf(e4.x, w[16], f); f = fmaf(e4.y, w[17], f);
    f = fmaf(e4.z, w[18], f); f = fmaf(e4.w, w[19], f);
    return f;
}

__global__ __launch_bounds__(128, 2) void gather_kernel(
    const float* __restrict__ x,       // [E][C]
    const float* __restrict__ rbf,     // [E][RBFD]
    const float* __restrict__ env,     // [E]
    const int*   __restrict__ perm,    // [E]
    const int*   __restrict__ own,     // [E]
    const float* __restrict__ Wrbf,    // [C][RBFD]
    const float* __restrict__ brbf,    // [C]
    float* __restrict__ acc)           // [N][C] (pre-zeroed)
{
    __shared__ int   e_s[SLAB];
    __shared__ float env_s[SLAB];
    __shared__ int   own_s[SLAB];
    __shared__ float rbf_s[2][SS][RBFD];

    const int tid = threadIdx.x;      // 0..127, = channel
    const int p0  = blockIdx.x * SLAB;

    {
        const int e = perm[p0 + tid];
        e_s[tid]   = e;
        env_s[tid] = env[e];
        own_s[tid] = own[p0 + tid];
    }

    float w[RBFD];
#pragma unroll
    for (int r = 0; r < RBFD; ++r) w[r] = Wrbf[tid * RBFD + r];
    const float bias = brbf[tid];

    __syncthreads();   // full drain: vmcnt == 0 baseline for our counting

    // pin w/bias live here so their loads cannot sink into the loop
    asm volatile("" ::
        "v"(w[0]), "v"(w[1]), "v"(w[2]), "v"(w[3]), "v"(w[4]),
        "v"(w[5]), "v"(w[6]), "v"(w[7]), "v"(w[8]), "v"(w[9]),
        "v"(w[10]), "v"(w[11]), "v"(w[12]), "v"(w[13]), "v"(w[14]),
        "v"(w[15]), "v"(w[16]), "v"(w[17]), "v"(w[18]), "v"(w[19]),
        "v"(bias));

    const int first_own = own_s[0];
    int   cur_own = first_own;
    float sum = 0.0f;

#define FLUSH()                                                                \
    do {                                                                       \
        if (cur_own == first_own)                                              \
            unsafeAtomicAdd(&acc[(size_t)cur_own * C + tid], sum);             \
        else acc[(size_t)cur_own * C + tid] = sum;                             \
    } while (0)

    float xA[SS], xB[SS], st[5];

    // issue 5 rbf staging loads (scattered dwords) for stage base sb
#define ISSUE_RBF(sb)                                                          \
    do {                                                                       \
        _Pragma("unroll")                                                      \
        for (int p = 0; p < 5; ++p) {                                          \
            const int g = p * 128 + tid;                                       \
            const float* ap = rbf + (size_t)e_s[(sb) + g / RBFD] * RBFD        \
                              + (g % RBFD);                                    \
            asm volatile("global_load_dword %0, %1, off"                       \
                         : "=v"(st[p]) : "v"(ap));                             \
        }                                                                      \
    } while (0)

    // issue 32 x loads for stage base sb into buffer XB
#define ISSUE_X(sb, XB)                                                        \
    do {                                                                       \
        _Pragma("unroll")                                                      \
        for (int i = 0; i < SS; ++i) {                                         \
            const float* ap = x + ((size_t)e_s[(sb) + i] << 7) + tid;          \
            asm volatile("global_load_dword %0, %1, off"                       \
                         : "=v"(XB[i]) : "v"(ap));                             \
        }                                                                      \
    } while (0)

    // consume 8 edges [j0, j0+8) of stage base sb from LDS buf B + x buf XB
#define CHUNK8(sb, j0, XB, B, WN)                                              \
    do {                                                                       \
        WAITV(WN);                                                             \
        __builtin_amdgcn_sched_barrier(0);                                     \
        _Pragma("unroll")                                                      \
        for (int j = (j0); j < (j0) + 8; ++j) {                                \
            const float f = filt20(&rbf_s[B][j][0], w, bias);                  \
            const float v = f * env_s[(sb) + j] * XB[j];                       \
            const int   o = own_s[(sb) + j];                                   \
            if (o != cur_own) { FLUSH(); sum = 0.0f; cur_own = o; }            \
            sum += v;                                                          \
        }                                                                      \
    } while (0)

    // write staged rbf to LDS buffer B, then barrier WITHOUT vmcnt drain
#define STAGE_DSWRITE(B)                                                       \
    do {                                                                       \
        WAITV(32);                                                             \
        __builtin_amdgcn_sched_barrier(0);                                     \
        _Pragma("unroll")                                                      \
        for (int p = 0; p < 5; ++p) {                                          \
            const int g = p * 128 + tid;                                       \
            rbf_s[B][g / RBFD][g % RBFD] = st[p];                              \
        }                                                                      \
        asm volatile("s_waitcnt lgkmcnt(0)" ::: "memory");                     \
        __builtin_amdgcn_sched_barrier(0);                                     \
        __builtin_amdgcn_s_barrier();                                          \
    } while (0)

    // ---- prologue: stage 0's loads ----
    ISSUE_RBF(0);
    ISSUE_X(0, xA);
    STAGE_DSWRITE(0);

    // ---- stage 0: issue stage-1 loads, consume stage 0 ----
    ISSUE_RBF(SS);
    ISSUE_X(SS, xB);
    __builtin_amdgcn_sched_barrier(0);
    CHUNK8(0, 0,  xA, 0, 61);
    CHUNK8(0, 8,  xA, 0, 53);
    CHUNK8(0, 16, xA, 0, 45);
    CHUNK8(0, 24, xA, 0, 37);
    STAGE_DSWRITE(1);

    // ---- stage 1 ----
    ISSUE_RBF(2 * SS);
    ISSUE_X(2 * SS, xA);
    __builtin_amdgcn_sched_barrier(0);
    CHUNK8(SS, 0,  xB, 1, 61);
    CHUNK8(SS, 8,  xB, 1, 53);
    CHUNK8(SS, 16, xB, 1, 45);
    CHUNK8(SS, 24, xB, 1, 37);
    STAGE_DSWRITE(0);

    // ---- stage 2 ----
    ISSUE_RBF(3 * SS);
    ISSUE_X(3 * SS, xB);
    __builtin_amdgcn_sched_barrier(0);
    CHUNK8(2 * SS, 0,  xA, 0, 61);
    CHUNK8(2 * SS, 8,  xA, 0, 53);
    CHUNK8(2 * SS, 16, xA, 0, 45);
    CHUNK8(2 * SS, 24, xA, 0, 37);
    STAGE_DSWRITE(1);

    // ---- stage 3 (last: no further issues) ----
    CHUNK8(3 * SS, 0,  xB, 1, 24);
    CHUNK8(3 * SS, 8,  xB, 1, 16);
    CHUNK8(3 * SS, 16, xB, 1, 8);
    CHUNK8(3 * SS, 24, xB, 1, 0);

    // final flush: cur_own may span into next slab -> atomic
    unsafeAtomicAdd(&acc[(size_t)cur_own * C + tid], sum);

#undef FLUSH
#undef ISSUE_RBF
#undef ISSUE_X
#undef CHUNK8
#undef STAGE_DSWRITE
}

// ---------------------------------------------------------------------------
// Fused MLP head (unchanged).
// ---------------------------------------------------------------------------
__device__ __forceinline__ float silu_f(float v) {
    return v * (1.0f / (1.0f + __expf(-v)));
}

__global__ __launch_bounds__(256) void mlp_head_kernel(
    const float* __restrict__ acc,   // [N][C]
    const float* __restrict__ W1T,   // [C][C]  (k-major)
    const float* __restrict__ b1,    // [C]
    const float* __restrict__ W2T,   // [C][C]
    const float* __restrict__ b2,    // [C]
    const float* __restrict__ W3,    // [1][C]
    const float* __restrict__ b3,    // [1]
    float* __restrict__ out,         // [N]
    int natoms)
{
    __shared__ float As[C][C + 1];

    const int tid = threadIdx.x;
    const int a0  = blockIdx.x * C;
    const int tc  = tid & 15;
    const int ta  = tid >> 4;
    const int abase = ta * 8;
    const int cbase = tc * 8;

    {
        const int sub = tid >> 7;
        const int k   = tid & 127;
        for (int pair = 0; pair < 64; ++pair) {
            const int al = pair * 2 + sub;
            const int a  = a0 + al;
            float v = (a < natoms) ? acc[(size_t)a * C + k] : 0.0f;
            As[k][al] = v;
        }
    }
    __syncthreads();

    float r[8][8];

    // layer 1
#pragma unroll
    for (int i = 0; i < 8; ++i)
#pragma unroll
        for (int j = 0; j < 8; ++j) r[i][j] = 0.0f;

#pragma unroll 2
    for (int k = 0; k < C; ++k) {
        float4 bq0 = *reinterpret_cast<const float4*>(W1T + k * C + cbase);
        float4 bq1 = *reinterpret_cast<const float4*>(W1T + k * C + cbase + 4);
        float bv[8] = {bq0.x, bq0.y, bq0.z, bq0.w, bq1.x, bq1.y, bq1.z, bq1.w};
        float av[8];
#pragma unroll
        for (int i = 0; i < 8; ++i) av[i] = As[k][abase + i];
#pragma unroll
        for (int i = 0; i < 8; ++i)
#pragma unroll
            for (int j = 0; j < 8; ++j) r[i][j] = fmaf(av[i], bv[j], r[i][j]);
    }

    __syncthreads();
    {
        float bb[8];
#pragma unroll
        for (int j = 0; j < 8; ++j) bb[j] = b1[cbase + j];
#pragma unroll
        for (int i = 0; i < 8; ++i)
#pragma unroll
            for (int j = 0; j < 8; ++j)
                As[cbase + j][abase + i] = silu_f(r[i][j] + bb[j]);
    }
    __syncthreads();

    // layer 2
#pragma unroll
    for (int i = 0; i < 8; ++i)
#pragma unroll
        for (int j = 0; j < 8; ++j) r[i][j] = 0.0f;

#pragma unroll 2
    for (int k = 0; k < C; ++k) {
        float4 bq0 = *reinterpret_cast<const float4*>(W2T + k * C + cbase);
        float4 bq1 = *reinterpret_cast<const float4*>(W2T + k * C + cbase + 4);
        float bv[8] = {bq0.x, bq0.y, bq0.z, bq0.w, bq1.x, bq1.y, bq1.z, bq1.w};
        float av[8];
#pragma unroll
        for (int i = 0; i < 8; ++i) av[i] = As[k][abase + i];
#pragma unroll
        for (int i = 0; i < 8; ++i)
#pragma unroll
            for (int j = 0; j < 8; ++j) r[i][j] = fmaf(av[i], bv[j], r[i][j]);
    }

    __syncthreads();

    // final: silu(.. + b2) . W3
    {
        float bb[8], w3v[8];
#pragma unroll
        for (int j = 0; j < 8; ++j) bb[j] = b2[cbase + j];
        float4 wq0 = *reinterpret_cast<const float4*>(W3 + cbase);
        float4 wq1 = *reinterpret_cast<const float4*>(W3 + cbase + 4);
        w3v[0]=wq0.x; w3v[1]=wq0.y; w3v[2]=wq0.z; w3v[3]=wq0.w;
        w3v[4]=wq1.x; w3v[5]=wq1.y; w3v[6]=wq1.z; w3v[7]=wq1.w;

#pragma unroll
        for (int i = 0; i < 8; ++i) {
            float p = 0.0f;
#pragma unroll
            for (int j = 0; j < 8; ++j)
                p = fmaf(silu_f(r[i][j] + bb[j]), w3v[j], p);
            As[abase + i][tc] = p;
        }
    }
    __syncthreads();

    if (tid < C) {
        const int a = a0 + tid;
        if (a < natoms) {
            float s = 0.0f;
#pragma unroll
            for (int t = 0; t < 16; ++t) s += As[tid][t];
            out[a] = s + b3[0];
        }
    }
}

// ---------------------------------------------------------------------------
extern "C" void kernel_launch(void* const* d_in, const int* in_sizes, int n_in,
                              void* d_out, int out_size, void* d_ws, size_t ws_size,
                              hipStream_t stream) {
    const float* x      = (const float*)d_in[0];
    const float* rbf    = (const float*)d_in[1];
    const float* env    = (const float*)d_in[2];
    const int*   idx    = (const int*)  d_in[3];
    const float* Wrbf   = (const float*)d_in[5];
    const float* brbf   = (const float*)d_in[6];
    const float* W1     = (const float*)d_in[7];
    const float* b1     = (const float*)d_in[8];
    const float* W2     = (const float*)d_in[9];
    const float* b2     = (const float*)d_in[10];
    const float* W3     = (const float*)d_in[11];
    const float* b3     = (const float*)d_in[12];
    float*       out    = (float*)d_out;

    const int E = in_sizes[0] / C;        // 800000
    const int N = NATOMS;                 // 50000
    const int nchunks = (N + SCAN_CHUNK - 1) / SCAN_CHUNK;   // 49

    // workspace layout
    float* acc     = (float*)d_ws;                    // N*C
    float* W1T     = acc + (size_t)N * C;             // C*C
    float* W2T     = W1T + C * C;                     // C*C
    int*   count   = (int*)(W2T + C * C);             // N
    int*   base    = count + N;                       // N+1
    int*   cursor  = base + (N + 1);                  // N
    int*   partial = cursor + N;                      // 64
    int*   perm    = partial + 64;                    // E
    int*   own     = perm + E;                        // E

    setup_kernel<<<2048, 256, 0, stream>>>(W1, W2, W1T, W2T, count,
                                           (float4*)acc, N, (N * C) / 4);

    histogram_kernel<<<(E + 255) / 256, 256, 0, stream>>>(idx, count, E);
    scan_partials_kernel<<<nchunks, 256, 0, stream>>>(count, partial, N);
    scan_chunkbase_kernel<<<1, 64, 0, stream>>>(partial, base, nchunks, N);
    scan_apply_kernel<<<nchunks, SCAN_CHUNK, 0, stream>>>(count, partial, base, cursor, N);
    fill_perm_kernel<<<(E + 255) / 256, 256, 0, stream>>>(idx, cursor, perm, own, E);

    gather_kernel<<<E / SLAB, 128, 0, stream>>>(x, rbf, env, perm, own,
                                                Wrbf, brbf, acc);

    const int tiles = (N + C - 1) / C;
    mlp_head_kernel<<<tiles, 256, 0, stream>>>(acc, W1T, b1, W2T, b2, W3, b3, out, N);
}